// Round 9
// baseline (101.352 us; speedup 1.0000x reference)
//
#include <hip/hip_runtime.h>

// CensusLoss = mean |census(pred)-census(target)| = mismatch_count / (8*48*512*512).
// Fused kernel, 64x64 block region as two 64x32 halves, 512 threads, RPT=4.
//
// Spill history (R4-R6): divergent wave-split pipelines spill ~90-170B/thread
// to scratch (WRITE_SIZE 44-47MB). R7 (no split) is clean at ~26us. This round
// adds overlap the spill-safe way: split staging into two disjoint LDS row
// ranges; hoist compute-A between stage-B and the barrier. Per-wave, stage-B
// temps die before compute-A (no live-range overlap); across waves, stage-B
// HBM drains overlap compute-A LDS/VALU (m114 wave-level overlap).
//
//   stageA rows 0..37 | sync | stageB rows 38..69 ; computeA | sync | computeB
//
// computeA touches halo rows <= 37 only; stageB writes rows >= 38 -> no race.
// LDS column-major [x][y], PITCH 72 + swizzle cbase(lx)=lx*72+4*((lx>>2)&7):
// columns 16B-aligned (b128 window reads, ~2-way = free), staged writes spread
// across all 8 bank-quads. 64x64 region -> halo factor 1.23 -> ~62MB fetch.

#define BATCH 8
#define HH 512
#define WW 512
#define PLANE (HH * WW)
#define TW 64
#define TH 64             // block pixel region (two 32-row halves)
#define SCOLS 72          // staged cols: gx = tx0-4+lx (f4-aligned)
#define HROWS 70          // halo rows:  gy = ty0-3+hy
#define AROWS 38          // stage-A: hy 0..37  (covers px rows 0..31)
#define BROWS 32          // stage-B: hy 38..69 (covers px rows 32..63)
#define KPR 18            // float4 chunks per halo row (72/4)
#define PITCH 72          // column length 70 + 2 pad; %4==0 -> 16B columns
#define NT 512
#define LDSZ (SCOLS * PITCH + 8)

__device__ __forceinline__ int refl(int v, int n) {
    return v < 0 ? -v : (v >= n ? 2 * n - 2 - v : v);
}
__device__ __forceinline__ int cbase(int lx) {      // swizzled column base
    return lx * PITCH + (((lx >> 2) & 7) << 2);     // stays 0 mod 4 -> 16B cols
}

// Load 10 consecutive column floats (16B-aligned) into registers.
__device__ __forceinline__ void load_col10(const float* col, float (&w)[10]) {
    const float4 a = *(const float4*)(col);
    const float4 b = *(const float4*)(col + 4);
    const float2 d = *(const float2*)(col + 8);
    w[0] = a.x; w[1] = a.y; w[2] = a.z; w[3] = a.w;
    w[4] = b.x; w[5] = b.y; w[6] = b.z; w[7] = b.w;
    w[8] = d.x; w[9] = d.y;
}

__global__ __launch_bounds__(NT, 4)
void census_fused(const float* __restrict__ pred,
                  const float* __restrict__ target,
                  float* __restrict__ out) {
    __shared__ __align__(16) float sP[LDSZ];
    __shared__ __align__(16) float sT[LDSZ];

    const int b   = blockIdx.z;
    const int ty0 = blockIdx.y * TH;
    const int tx0 = blockIdx.x * TW;
    const float* __restrict__ pb = pred   + (size_t)b * 3 * PLANE;
    const float* __restrict__ tb = target + (size_t)b * 3 * PLANE;
    const bool fastx = (blockIdx.x >= 1 && blockIdx.x <= 6);  // gx always in range

    auto stage_f4 = [&](int hy, int k) {
        const int gy  = refl(ty0 + hy - 3, HH);
        const int off = gy * WW + tx0 - 4 + 4 * k;            // 16B-aligned
        const float4 pr = *(const float4*)(pb + off);
        const float4 pg = *(const float4*)(pb + off + PLANE);
        const float4 pc = *(const float4*)(pb + off + 2 * PLANE);
        const float4 tr = *(const float4*)(tb + off);
        const float4 tg = *(const float4*)(tb + off + PLANE);
        const float4 tc = *(const float4*)(tb + off + 2 * PLANE);
        const int lx = 4 * k;
        sP[cbase(lx + 0) + hy] = 0.299f * pr.x + 0.587f * pg.x + 0.114f * pc.x;
        sP[cbase(lx + 1) + hy] = 0.299f * pr.y + 0.587f * pg.y + 0.114f * pc.y;
        sP[cbase(lx + 2) + hy] = 0.299f * pr.z + 0.587f * pg.z + 0.114f * pc.z;
        sP[cbase(lx + 3) + hy] = 0.299f * pr.w + 0.587f * pg.w + 0.114f * pc.w;
        sT[cbase(lx + 0) + hy] = 0.299f * tr.x + 0.587f * tg.x + 0.114f * tc.x;
        sT[cbase(lx + 1) + hy] = 0.299f * tr.y + 0.587f * tg.y + 0.114f * tc.y;
        sT[cbase(lx + 2) + hy] = 0.299f * tr.z + 0.587f * tg.z + 0.114f * tc.z;
        sT[cbase(lx + 3) + hy] = 0.299f * tr.w + 0.587f * tg.w + 0.114f * tc.w;
    };
    auto stage_sc = [&](int hy, int lx) {
        const int gy  = refl(ty0 + hy - 3, HH);
        const int gx  = refl(tx0 + lx - 4, WW);
        const int off = gy * WW + gx;
        sP[cbase(lx) + hy] = 0.299f * pb[off] + 0.587f * pb[off + PLANE] + 0.114f * pb[off + 2 * PLANE];
        sT[cbase(lx) + hy] = 0.299f * tb[off] + 0.587f * tb[off + PLANE] + 0.114f * tb[off + 2 * PLANE];
    };

    // ---- stage A: halo rows 0..37 ----
    if (fastx) {
        for (int idx = threadIdx.x; idx < AROWS * KPR; idx += NT) {
            const int hy = idx / KPR;
            stage_f4(hy, idx - hy * KPR);
        }
    } else {
        for (int idx = threadIdx.x; idx < AROWS * SCOLS; idx += NT) {
            const int hy = idx / SCOLS;
            stage_sc(hy, idx - hy * SCOLS);
        }
    }
    __syncthreads();

    // ---- stage B: halo rows 38..69 (disjoint from compute-A's reads) ----
    if (fastx) {
        for (int idx = threadIdx.x; idx < BROWS * KPR; idx += NT) {
            const int hy = idx / KPR;
            stage_f4(AROWS + hy, idx - hy * KPR);
        }
    } else {
        for (int idx = threadIdx.x; idx < BROWS * SCOLS; idx += NT) {
            const int hy = idx / SCOLS;
            stage_sc(AROWS + hy, idx - hy * SCOLS);
        }
    }

    const int wv  = threadIdx.x >> 6;   // wave == 4-row band
    const int c   = threadIdx.x & 63;   // pixel column in tile
    const int pr0 = wv * 4;             // band origin within a half (0,4,..,28)

    // Count mismatches for px rows r0..r0+3 (halo rows r0..r0+9), r0 % 4 == 0.
    auto band_count = [&](int r0) -> int {
        float wP[10], wT[10], cP[4], cT[4];
        int cnt = 0;
        load_col10(&sP[cbase(c + 4) + r0], wP);     // dx = 0 column (holds centers)
        load_col10(&sT[cbase(c + 4) + r0], wT);
        #pragma unroll
        for (int p = 0; p < 4; ++p) { cP[p] = wP[3 + p]; cT[p] = wT[3 + p]; }
        #pragma unroll
        for (int p = 0; p < 4; ++p) {
            #pragma unroll
            for (int dy = -3; dy <= 3; ++dy) {
                if (dy == 0) continue;              // skip center
                cnt += ((cP[p] > wP[3 + p + dy]) != (cT[p] > wT[3 + p + dy])) ? 1 : 0;
            }
        }
        #pragma unroll
        for (int t = 0; t < 6; ++t) {
            const int lx = c + 1 + (t < 3 ? t : t + 1);   // dx = -3..3, dx != 0
            load_col10(&sP[cbase(lx) + r0], wP);
            load_col10(&sT[cbase(lx) + r0], wT);
            #pragma unroll
            for (int p = 0; p < 4; ++p) {
                #pragma unroll
                for (int dy = -3; dy <= 3; ++dy)
                    cnt += ((cP[p] > wP[3 + p + dy]) != (cT[p] > wT[3 + p + dy])) ? 1 : 0;
            }
        }
        return cnt;
    };

    // compute A (halo rows <= 37, staged before first barrier); waves still
    // draining stage-B loads overlap with waves already computing here.
    int cnt = band_count(pr0);
    __syncthreads();                    // stage-B visible
    cnt += band_count(32 + pr0);        // compute B (halo rows 32..69)

    // Reduce: 64-lane shuffle, cross-wave LDS, one atomic per block.
    #pragma unroll
    for (int o = 32; o > 0; o >>= 1) cnt += __shfl_down(cnt, o, 64);
    __shared__ int wsum[8];
    if ((threadIdx.x & 63) == 0) wsum[wv] = cnt;
    __syncthreads();
    if (threadIdx.x == 0) {
        int tot = 0;
        #pragma unroll
        for (int w = 0; w < 8; ++w) tot += wsum[w];
        // N = 8 * 48 * 512 * 512 = 100663296
        atomicAdd(out, (float)tot * (1.0f / 100663296.0f));
    }
}

extern "C" void kernel_launch(void* const* d_in, const int* in_sizes, int n_in,
                              void* d_out, int out_size, void* d_ws, size_t ws_size,
                              hipStream_t stream) {
    const float* pred   = (const float*)d_in[0];
    const float* target = (const float*)d_in[1];
    float* out = (float*)d_out;

    hipMemsetAsync(out, 0, sizeof(float), stream);   // d_out poisoned 0xAA

    dim3 grid(WW / TW, HH / TH, BATCH);              // (8, 8, 8) = 512 blocks
    census_fused<<<grid, NT, 0, stream>>>(pred, target, out);
}